// Round 9
// baseline (27.333 us; speedup 1.0000x reference)
//
#include <hip/hip_runtime.h>

// SuperResolve: A=4 frames, n=4, c=3, h=w=256, S=2 -> out (4,3,512,512) fp32
// R9 = R8 structure with:
//  (1) Sterbenz-exact dy/dx restored (posr=fma(off,2,2row); dy=posr-2y0):
//      bit-identical to numpy's radius masks. R8's folded form flipped
//      mask boundaries (absmax 0.0019 -> 0.0273, 2% margin). MANDATORY.
//  (2) fminf clamp dropped: max dist = 4*2+4*0.4+4*2 = 17.6 < 20 given input
//      ranges (o11,o22<=2, |o12|,|o21|<=0.2, |dxLR|<=2) -> clip never fires.
//  (3) __launch_bounds__(256,8): target VGPR<=64 -> 8 waves/SIMD (VGPR quantum:
//      8 waves at <=64, only 4 at 65..128; R8 at ~80 ran half-occupancy).
//      Revert if WRITE_SIZE shows spills (>12288 KB).
// R3: cap 32 VGPR = disaster. R4: >=2048 blocks. R6: SGPR plane bases.
// R7: LDS staging regressed. R8: raw v_exp_f32, q-premask.

#define AF      4
#define NB      4
#define CH      3
#define H       256
#define W       256
#define SH      512
#define SW      512
#define HW      (H*W)
#define SHW     (SH*SW)
#define RADIUS  4.0f
// 0.25 (LR displacement scaling) * 0.5*log2(e): weight = exp2(-dist')
#define MSCALE  0.18033688011112042f

__global__ __launch_bounds__(256, 8) void superresolve_kernel(
    const float* __restrict__ alts,     // [AF][NB][CH][H][W]
    const float* __restrict__ offsets,  // [AF][NB][2][H][W]
    const float* __restrict__ qs,       // [AF][NB][H][W]
    const float* __restrict__ o11,      // [NB][SH][SW]
    const float* __restrict__ o12,
    const float* __restrict__ o21,
    const float* __restrict__ o22,
    float* __restrict__ out)            // [NB][CH][SH][SW]
{
    __shared__ float red[128 * 17];     // stride 17 words: conflict-free

    const int tid   = threadIdx.x;
    const int wv    = tid >> 6;
    const int lane  = tid & 63;
    const int fpair = wv >> 1;                  // 0: frames {0,1}; 1: {2,3}
    const int pix   = ((wv & 1) << 6) + lane;   // 0..127

    // bijective XCD swizzle over 2048 blocks
    const int bid = blockIdx.x;
    const int swz = (bid & 7) * 256 + (bid >> 3);
    const int P   = swz * 128 + pix;            // linear LR pixel id

    const int x0 = P & (W - 1);
    // wave-uniform -> SGPRs
    const int y0  = __builtin_amdgcn_readfirstlane((P >> 8) & (H - 1));
    const int nn  = __builtin_amdgcn_readfirstlane(P >> 16);
    const int af0 = __builtin_amdgcn_readfirstlane(fpair << 1);

    const bool bL = (x0 > 0);
    const bool bR = (x0 < W - 1);
    const int  xL = bL ? x0 - 1 : 0;
    const int  xR = bR ? x0 + 1 : W - 1;
    const int  iL = y0 * W + xL;
    const int  iC = y0 * W + x0;
    const int  iR = y0 * W + xR;
    const float f2xL = (float)(2 * xL);
    const float f2xC = (float)(2 * x0);
    const float f2xR = (float)(2 * xR);
    const float xf0  = f2xC;
    const float yf0  = (float)(2 * y0);

    // per-subpixel o-matrices (float2 loads, coalesced)
    const int obase = (nn * SH + 2 * y0) * SW + 2 * x0;
    const float2 v11a = *(const float2*)(o11 + obase);
    const float2 v11b = *(const float2*)(o11 + obase + SW);
    const float2 v12a = *(const float2*)(o12 + obase);
    const float2 v12b = *(const float2*)(o12 + obase + SW);
    const float2 v21a = *(const float2*)(o21 + obase);
    const float2 v21b = *(const float2*)(o21 + obase + SW);
    const float2 v22a = *(const float2*)(o22 + obase);
    const float2 v22b = *(const float2*)(o22 + obase + SW);

    float m11s[2][2], m12s[2][2], m22s[2][2];
    m11s[0][0] = MSCALE * v11a.x;  m11s[0][1] = MSCALE * v11a.y;
    m11s[1][0] = MSCALE * v11b.x;  m11s[1][1] = MSCALE * v11b.y;
    m12s[0][0] = MSCALE * (v12a.x + v21a.x);  m12s[0][1] = MSCALE * (v12a.y + v21a.y);
    m12s[1][0] = MSCALE * (v12b.x + v21b.x);  m12s[1][1] = MSCALE * (v12b.y + v21b.y);
    m22s[0][0] = MSCALE * v22a.x;  m22s[0][1] = MSCALE * v22a.y;
    m22s[1][0] = MSCALE * v22b.x;  m22s[1][1] = MSCALE * v22b.y;

    float sumw[2][2] = {{0.f,0.f},{0.f,0.f}};
    float acc0[2][2] = {{0.f,0.f},{0.f,0.f}};
    float acc1[2][2] = {{0.f,0.f},{0.f,0.f}};
    float acc2[2][2] = {{0.f,0.f},{0.f,0.f}};

    // COLK: one (a,row,column) contribution to all 4 subpixels.
    // dy/dx Sterbenz-exact (bit-identical masks to np). q_ pre-masked for
    // column bounds. No dist clamp (never fires for these input ranges).
#define COLK(or_, oc_, q_, a0_, a1_, a2_, f2x_, IS_L, NEED_VY)                \
    {                                                                         \
        const float posr = fmaf(or_, 2.0f, rowf);                             \
        const float dy0v = posr - yf0;                                        \
        const float dy1v = dy0v - 1.0f;                                       \
        const float posc = fmaf(oc_, 2.0f, f2x_);                             \
        const float dx0v = posc - xf0;                                        \
        const float dx1v = dx0v - 1.0f;                                       \
        const bool vx1 = !(IS_L) || (dx1v >= -RADIUS);                        \
        const bool vyb = !(NEED_VY) || (dy1v >= -RADIUS);                     \
        _Pragma("unroll")                                                     \
        for (int sy = 0; sy < 2; ++sy) {                                      \
            const float dyv = sy ? dy1v : dy0v;                               \
            const float dy2 = dyv * dyv;                                      \
            _Pragma("unroll")                                                 \
            for (int sx = 0; sx < 2; ++sx) {                                  \
                const float dxv = sx ? dx1v : dx0v;                           \
                const float u = fmaf(dyv, m12s[sy][sx], dxv * m11s[sy][sx]);  \
                const float d = fmaf(dxv, u, dy2 * m22s[sy][sx]);             \
                float w = __builtin_amdgcn_exp2f(-d) * (q_);                  \
                if (IS_L && sx == 1)    w = vx1 ? w : 0.0f;                   \
                if (NEED_VY && sy == 1) w = vyb ? w : 0.0f;                   \
                sumw[sy][sx] += w;                                            \
                acc0[sy][sx] = fmaf(w, a0_, acc0[sy][sx]);                    \
                acc1[sy][sx] = fmaf(w, a1_, acc1[sy][sx]);                    \
                acc2[sy][sx] = fmaf(w, a2_, acc2[sy][sx]);                    \
            }                                                                 \
        }                                                                     \
    }

    #pragma unroll
    for (int ai = 0; ai < 2; ++ai) {
        const int a = af0 + ai;   // wave-uniform scalar
        const float* offbR = offsets + (size_t)(a * NB + nn) * 2 * HW;
        const float* offbC = offbR + HW;
        const float* qb    = qs   + (size_t)(a * NB + nn) * HW;
        const float* ab0   = alts + (size_t)(a * NB + nn) * CH * HW;
        const float* ab1   = ab0 + HW;
        const float* ab2   = ab0 + 2 * HW;

        #pragma unroll
        for (int dr = 0; dr < 3; ++dr) {        // dr = di + 1
            if (dr == 0 && y0 == 0) continue;   // scalar uniform skip
            if (dr == 2 && y0 == H - 1) continue;
            const int ro = (dr - 1) * W;        // scalar row offset
            const float* pR = offbR + ro;
            const float* pC = offbC + ro;
            const float* pQ = qb + ro;
            const float* p0 = ab0 + ro;
            const float* p1 = ab1 + ro;
            const float* p2 = ab2 + ro;
            const float rowf = (float)(2 * (y0 + dr - 1));

            // 18 batched gathers (saddr + {iL,iC,iR})
            const float orL = pR[iL], orC = pR[iC], orR = pR[iR];
            const float ocL = pC[iL], ocC = pC[iC], ocR = pC[iR];
            const float qL  = pQ[iL], qC  = pQ[iC], qR  = pQ[iR];
            const float aL0 = p0[iL], aC0 = p0[iC], aR0 = p0[iR];
            const float aL1 = p1[iL], aC1 = p1[iC], aR1 = p1[iR];
            const float aL2 = p2[iL], aC2 = p2[iC], aR2 = p2[iR];

            // column-bounds masks folded into q (once, not per subpixel)
            const float qLm = bL ? qL : 0.0f;
            const float qRm = bR ? qR : 0.0f;

            const bool needvy = (dr == 0);
            COLK(orL, ocL, qLm, aL0, aL1, aL2, f2xL, true,  needvy)
            COLK(orC, ocC, qC,  aC0, aC1, aC2, f2xC, false, needvy)
            COLK(orR, ocR, qRm, aR0, aR1, aR2, f2xR, false, needvy)
        }
    }
#undef COLK

    // cross-fpair reduction: fpair 1 writes 16 floats/pixel, fpair 0 sums+stores
    if (fpair == 1) {
        float* r = &red[pix * 17];
        #pragma unroll
        for (int sy = 0; sy < 2; ++sy)
            #pragma unroll
            for (int sx = 0; sx < 2; ++sx) {
                const int s = sy * 2 + sx;
                r[s]      = sumw[sy][sx];
                r[4 + s]  = acc0[sy][sx];
                r[8 + s]  = acc1[sy][sx];
                r[12 + s] = acc2[sy][sx];
            }
    }
    __syncthreads();
    if (fpair == 0) {
        const float* r = &red[pix * 17];
        #pragma unroll
        for (int sy = 0; sy < 2; ++sy)
            #pragma unroll
            for (int sx = 0; sx < 2; ++sx) {
                const int s = sy * 2 + sx;
                sumw[sy][sx] += r[s];
                acc0[sy][sx] += r[4 + s];
                acc1[sy][sx] += r[8 + s];
                acc2[sy][sx] += r[12 + s];
            }
        const size_t ob = (size_t)(nn * CH) * SHW + (size_t)(2 * y0) * SW + 2 * x0;
        #pragma unroll
        for (int sy = 0; sy < 2; ++sy) {
            const float i0 = 1.0f / sumw[sy][0];
            const float i1 = 1.0f / sumw[sy][1];
            *(float2*)(out + ob + (size_t)sy * SW) =
                make_float2(acc0[sy][0] * i0, acc0[sy][1] * i1);
            *(float2*)(out + ob + (size_t)sy * SW + SHW) =
                make_float2(acc1[sy][0] * i0, acc1[sy][1] * i1);
            *(float2*)(out + ob + (size_t)sy * SW + 2 * SHW) =
                make_float2(acc2[sy][0] * i0, acc2[sy][1] * i1);
        }
    }
}

extern "C" void kernel_launch(void* const* d_in, const int* in_sizes, int n_in,
                              void* d_out, int out_size, void* d_ws, size_t ws_size,
                              hipStream_t stream) {
    const float* alts    = (const float*)d_in[0];
    const float* offsets = (const float*)d_in[1];
    const float* qs      = (const float*)d_in[2];
    const float* o11     = (const float*)d_in[3];
    const float* o12     = (const float*)d_in[4];
    const float* o21     = (const float*)d_in[5];
    const float* o22     = (const float*)d_in[6];
    float* out = (float*)d_out;

    const int total_threads = NB * H * W * 2;   // 524,288
    const int block = 256;
    const int grid  = total_threads / block;    // 2048
    superresolve_kernel<<<grid, block, 0, stream>>>(alts, offsets, qs,
                                                    o11, o12, o21, o22, out);
}

// Round 10
// 24.212 us; speedup vs baseline: 1.1289x; 1.1289x over previous
//
#include <hip/hip_runtime.h>

// SuperResolve: A=4 frames, n=4, c=3, h=w=256, S=2 -> out (4,3,512,512) fp32
// R10 = R8-uncapped + R9 Sterbenz-exact masks + dwordx4 gather compression:
//  - per (a,plane,row): ONE unaligned global_load_dwordx4 at x0-1 gives
//    [L,C,R,_] -> 36 VMEM/thread (was 108). 2 cndmask/plane realign x0==0.
//  - waves with y0 >= H-2 (16/2048 blocks) use the scalar 3-load path so no
//    read ever crosses the end of a page-multiple input buffer.
//  - __launch_bounds__(256) uncapped: R9's (256,8) cap regressed 23.6->27.3.
// R3: VGPR caps cause spills. R6: SGPR plane bases. R7: LDS staging loses.
// R8: raw v_exp_f32, q-premask, no dist clamp (never fires: max 17.6 < 20).
// R9: dy/dx MUST be pos-then-subtract (mask bit-exactness vs numpy).

#define AF      4
#define NB      4
#define CH      3
#define H       256
#define W       256
#define SH      512
#define SW      512
#define HW      (H*W)
#define SHW     (SH*SW)
#define RADIUS  4.0f
// 0.25 (LR displacement scaling) * 0.5*log2(e): weight = exp2(-dist')
#define MSCALE  0.18033688011112042f

typedef float f4v __attribute__((ext_vector_type(4)));

static __device__ __forceinline__ f4v ld4(const float* p) {
    f4v v;
    __builtin_memcpy(&v, p, 16);    // align-4 16B load -> global_load_dwordx4
    return v;
}

__global__ __launch_bounds__(256) void superresolve_kernel(
    const float* __restrict__ alts,     // [AF][NB][CH][H][W]
    const float* __restrict__ offsets,  // [AF][NB][2][H][W]
    const float* __restrict__ qs,       // [AF][NB][H][W]
    const float* __restrict__ o11,      // [NB][SH][SW]
    const float* __restrict__ o12,
    const float* __restrict__ o21,
    const float* __restrict__ o22,
    float* __restrict__ out)            // [NB][CH][SH][SW]
{
    __shared__ float red[128 * 17];     // stride 17 words: conflict-free

    const int tid   = threadIdx.x;
    const int wv    = tid >> 6;
    const int lane  = tid & 63;
    const int fpair = wv >> 1;                  // 0: frames {0,1}; 1: {2,3}
    const int pix   = ((wv & 1) << 6) + lane;   // 0..127

    // bijective XCD swizzle over 2048 blocks
    const int bid = blockIdx.x;
    const int swz = (bid & 7) * 256 + (bid >> 3);
    const int P   = swz * 128 + pix;            // linear LR pixel id

    const int x0 = P & (W - 1);
    // wave-uniform -> SGPRs
    const int y0  = __builtin_amdgcn_readfirstlane((P >> 8) & (H - 1));
    const int nn  = __builtin_amdgcn_readfirstlane(P >> 16);
    const int af0 = __builtin_amdgcn_readfirstlane(fpair << 1);

    const bool bL = (x0 > 0);
    const bool bR = (x0 < W - 1);
    const int  xL = bL ? x0 - 1 : 0;
    const int  xR = bR ? x0 + 1 : W - 1;
    const int  iL = y0 * W + xL;
    const int  iC = y0 * W + x0;
    const int  iR = y0 * W + xR;
    const int  ib = y0 * W + (bL ? x0 - 1 : x0);   // dwordx4 window base
    const float f2xL = (float)(2 * xL);
    const float f2xC = (float)(2 * x0);
    const float f2xR = (float)(2 * xR);
    const float xf0  = f2xC;
    const float yf0  = (float)(2 * y0);

    // per-subpixel o-matrices (float2 loads, coalesced)
    const int obase = (nn * SH + 2 * y0) * SW + 2 * x0;
    const float2 v11a = *(const float2*)(o11 + obase);
    const float2 v11b = *(const float2*)(o11 + obase + SW);
    const float2 v12a = *(const float2*)(o12 + obase);
    const float2 v12b = *(const float2*)(o12 + obase + SW);
    const float2 v21a = *(const float2*)(o21 + obase);
    const float2 v21b = *(const float2*)(o21 + obase + SW);
    const float2 v22a = *(const float2*)(o22 + obase);
    const float2 v22b = *(const float2*)(o22 + obase + SW);

    float m11s[2][2], m12s[2][2], m22s[2][2];
    m11s[0][0] = MSCALE * v11a.x;  m11s[0][1] = MSCALE * v11a.y;
    m11s[1][0] = MSCALE * v11b.x;  m11s[1][1] = MSCALE * v11b.y;
    m12s[0][0] = MSCALE * (v12a.x + v21a.x);  m12s[0][1] = MSCALE * (v12a.y + v21a.y);
    m12s[1][0] = MSCALE * (v12b.x + v21b.x);  m12s[1][1] = MSCALE * (v12b.y + v21b.y);
    m22s[0][0] = MSCALE * v22a.x;  m22s[0][1] = MSCALE * v22a.y;
    m22s[1][0] = MSCALE * v22b.x;  m22s[1][1] = MSCALE * v22b.y;

    float sumw[2][2] = {{0.f,0.f},{0.f,0.f}};
    float acc0[2][2] = {{0.f,0.f},{0.f,0.f}};
    float acc1[2][2] = {{0.f,0.f},{0.f,0.f}};
    float acc2[2][2] = {{0.f,0.f},{0.f,0.f}};

    // COLK: one (a,row,column) contribution to all 4 subpixels.
    // dy/dx Sterbenz-exact (bit-identical masks to np). q_ pre-masked for
    // column bounds. No dist clamp (never fires for these input ranges).
#define COLK(or_, oc_, q_, a0_, a1_, a2_, f2x_, IS_L, NEED_VY)                \
    {                                                                         \
        const float posr = fmaf(or_, 2.0f, rowf);                             \
        const float dy0v = posr - yf0;                                        \
        const float dy1v = dy0v - 1.0f;                                       \
        const float posc = fmaf(oc_, 2.0f, f2x_);                             \
        const float dx0v = posc - xf0;                                        \
        const float dx1v = dx0v - 1.0f;                                       \
        const bool vx1 = !(IS_L) || (dx1v >= -RADIUS);                        \
        const bool vyb = !(NEED_VY) || (dy1v >= -RADIUS);                     \
        _Pragma("unroll")                                                     \
        for (int sy = 0; sy < 2; ++sy) {                                      \
            const float dyv = sy ? dy1v : dy0v;                               \
            const float dy2 = dyv * dyv;                                      \
            _Pragma("unroll")                                                 \
            for (int sx = 0; sx < 2; ++sx) {                                  \
                const float dxv = sx ? dx1v : dx0v;                           \
                const float u = fmaf(dyv, m12s[sy][sx], dxv * m11s[sy][sx]);  \
                const float d = fmaf(dxv, u, dy2 * m22s[sy][sx]);             \
                float w = __builtin_amdgcn_exp2f(-d) * (q_);                  \
                if (IS_L && sx == 1)    w = vx1 ? w : 0.0f;                   \
                if (NEED_VY && sy == 1) w = vyb ? w : 0.0f;                   \
                sumw[sy][sx] += w;                                            \
                acc0[sy][sx] = fmaf(w, a0_, acc0[sy][sx]);                    \
                acc1[sy][sx] = fmaf(w, a1_, acc1[sy][sx]);                    \
                acc2[sy][sx] = fmaf(w, a2_, acc2[sy][sx]);                    \
            }                                                                 \
        }                                                                     \
    }

    // MAIN_LOOP(FAST): FAST=1 -> 6 dwordx4 loads/group + 2 cndmask/plane;
    // FAST=0 -> 18 scalar loads (safe near buffer ends).
#define MAIN_LOOP(FAST)                                                       \
    _Pragma("unroll")                                                         \
    for (int ai = 0; ai < 2; ++ai) {                                          \
        const int a = af0 + ai;                                               \
        const float* offbR = offsets + (size_t)(a * NB + nn) * 2 * HW;        \
        const float* offbC = offbR + HW;                                      \
        const float* qb    = qs   + (size_t)(a * NB + nn) * HW;               \
        const float* ab0   = alts + (size_t)(a * NB + nn) * CH * HW;          \
        const float* ab1   = ab0 + HW;                                        \
        const float* ab2   = ab0 + 2 * HW;                                    \
        _Pragma("unroll")                                                     \
        for (int dr = 0; dr < 3; ++dr) {                                      \
            if (dr == 0 && y0 == 0) continue;                                 \
            if (dr == 2 && y0 == H - 1) continue;                             \
            const int ro = (dr - 1) * W;                                      \
            const float rowf = (float)(2 * (y0 + dr - 1));                    \
            float orL, orC, orR, ocL, ocC, ocR, qL, qC, qR;                   \
            float aL0, aC0, aR0, aL1, aC1, aR1, aL2, aC2, aR2;                \
            if (FAST) {                                                       \
                const f4v vR = ld4(offbR + ro + ib);                          \
                const f4v vC = ld4(offbC + ro + ib);                          \
                const f4v vQ = ld4(qb    + ro + ib);                          \
                const f4v w0 = ld4(ab0   + ro + ib);                          \
                const f4v w1 = ld4(ab1   + ro + ib);                          \
                const f4v w2 = ld4(ab2   + ro + ib);                          \
                orL = vR.x; orC = bL ? vR.y : vR.x; orR = bL ? vR.z : vR.y;   \
                ocL = vC.x; ocC = bL ? vC.y : vC.x; ocR = bL ? vC.z : vC.y;   \
                qL  = vQ.x; qC  = bL ? vQ.y : vQ.x; qR  = bL ? vQ.z : vQ.y;  \
                aL0 = w0.x; aC0 = bL ? w0.y : w0.x; aR0 = bL ? w0.z : w0.y;   \
                aL1 = w1.x; aC1 = bL ? w1.y : w1.x; aR1 = bL ? w1.z : w1.y;   \
                aL2 = w2.x; aC2 = bL ? w2.y : w2.x; aR2 = bL ? w2.z : w2.y;   \
            } else {                                                          \
                const float* pR = offbR + ro;                                 \
                const float* pC = offbC + ro;                                 \
                const float* pQ = qb + ro;                                    \
                const float* p0 = ab0 + ro;                                   \
                const float* p1 = ab1 + ro;                                   \
                const float* p2 = ab2 + ro;                                   \
                orL = pR[iL]; orC = pR[iC]; orR = pR[iR];                     \
                ocL = pC[iL]; ocC = pC[iC]; ocR = pC[iR];                     \
                qL  = pQ[iL]; qC  = pQ[iC]; qR  = pQ[iR];                     \
                aL0 = p0[iL]; aC0 = p0[iC]; aR0 = p0[iR];                     \
                aL1 = p1[iL]; aC1 = p1[iC]; aR1 = p1[iR];                     \
                aL2 = p2[iL]; aC2 = p2[iC]; aR2 = p2[iR];                     \
            }                                                                 \
            const float qLm = bL ? qL : 0.0f;                                 \
            const float qRm = bR ? qR : 0.0f;                                 \
            const bool needvy = (dr == 0);                                    \
            COLK(orL, ocL, qLm, aL0, aL1, aL2, f2xL, true,  needvy)           \
            COLK(orC, ocC, qC,  aC0, aC1, aC2, f2xC, false, needvy)           \
            COLK(orR, ocR, qRm, aR0, aR1, aR2, f2xR, false, needvy)           \
        }                                                                     \
    }

    if (y0 < H - 2) {          // rows reached <= 254: dwordx4 window in-plane
        MAIN_LOOP(1)
    } else {                   // y0 in {254,255}: touches row 255 -> scalar
        MAIN_LOOP(0)
    }
#undef MAIN_LOOP
#undef COLK

    // cross-fpair reduction: fpair 1 writes 16 floats/pixel, fpair 0 sums+stores
    if (fpair == 1) {
        float* r = &red[pix * 17];
        #pragma unroll
        for (int sy = 0; sy < 2; ++sy)
            #pragma unroll
            for (int sx = 0; sx < 2; ++sx) {
                const int s = sy * 2 + sx;
                r[s]      = sumw[sy][sx];
                r[4 + s]  = acc0[sy][sx];
                r[8 + s]  = acc1[sy][sx];
                r[12 + s] = acc2[sy][sx];
            }
    }
    __syncthreads();
    if (fpair == 0) {
        const float* r = &red[pix * 17];
        #pragma unroll
        for (int sy = 0; sy < 2; ++sy)
            #pragma unroll
            for (int sx = 0; sx < 2; ++sx) {
                const int s = sy * 2 + sx;
                sumw[sy][sx] += r[s];
                acc0[sy][sx] += r[4 + s];
                acc1[sy][sx] += r[8 + s];
                acc2[sy][sx] += r[12 + s];
            }
        const size_t ob = (size_t)(nn * CH) * SHW + (size_t)(2 * y0) * SW + 2 * x0;
        #pragma unroll
        for (int sy = 0; sy < 2; ++sy) {
            const float i0 = 1.0f / sumw[sy][0];
            const float i1 = 1.0f / sumw[sy][1];
            *(float2*)(out + ob + (size_t)sy * SW) =
                make_float2(acc0[sy][0] * i0, acc0[sy][1] * i1);
            *(float2*)(out + ob + (size_t)sy * SW + SHW) =
                make_float2(acc1[sy][0] * i0, acc1[sy][1] * i1);
            *(float2*)(out + ob + (size_t)sy * SW + 2 * SHW) =
                make_float2(acc2[sy][0] * i0, acc2[sy][1] * i1);
        }
    }
}

extern "C" void kernel_launch(void* const* d_in, const int* in_sizes, int n_in,
                              void* d_out, int out_size, void* d_ws, size_t ws_size,
                              hipStream_t stream) {
    const float* alts    = (const float*)d_in[0];
    const float* offsets = (const float*)d_in[1];
    const float* qs      = (const float*)d_in[2];
    const float* o11     = (const float*)d_in[3];
    const float* o12     = (const float*)d_in[4];
    const float* o21     = (const float*)d_in[5];
    const float* o22     = (const float*)d_in[6];
    float* out = (float*)d_out;

    const int total_threads = NB * H * W * 2;   // 524,288
    const int block = 256;
    const int grid  = total_threads / block;    // 2048
    superresolve_kernel<<<grid, block, 0, stream>>>(alts, offsets, qs,
                                                    o11, o12, o21, o22, out);
}

// Round 11
// 23.847 us; speedup vs baseline: 1.1462x; 1.0153x over previous
//
#include <hip/hip_runtime.h>

// SuperResolve: A=4 frames, n=4, c=3, h=w=256, S=2 -> out (4,3,512,512) fp32
// R11: 4-way frame split. Block = 256 thr = 4 waves; wave w = frame w over the
// SAME 64 pixels (quarter row, y0/nn/a wave-uniform -> SGPR plane bases).
// Per-thread: 9 COLKs, 27 scalar gathers, 16 accs -> target VGPR <= 64 for
// 8 waves/SIMD (occupancy quantum steps at 64). 4096 blocks = 16 blocks/CU.
// 3-writer LDS reduction (stride 17, conflict-free), wave 0 finalizes.
// R3/R9: never force-cap VGPR (spills / ILP loss). R8: raw v_exp_f32,
// q-premask, no dist clamp (max 17.6 < 20). R9: dy/dx pos-then-subtract
// (Sterbenz; mask bit-exact vs numpy). R10: dwordx4+cndmask = wash vs scalar
// loads (cndmask eats VALU pipe; scalar loads only cost issue slots).

#define AF      4
#define NB      4
#define CH      3
#define H       256
#define W       256
#define SH      512
#define SW      512
#define HW      (H*W)
#define SHW     (SH*SW)
#define RADIUS  4.0f
// 0.25 (LR displacement scaling) * 0.5*log2(e): weight = exp2(-dist')
#define MSCALE  0.18033688011112042f

__global__ __launch_bounds__(256) void superresolve_kernel(
    const float* __restrict__ alts,     // [AF][NB][CH][H][W]
    const float* __restrict__ offsets,  // [AF][NB][2][H][W]
    const float* __restrict__ qs,       // [AF][NB][H][W]
    const float* __restrict__ o11,      // [NB][SH][SW]
    const float* __restrict__ o12,
    const float* __restrict__ o21,
    const float* __restrict__ o22,
    float* __restrict__ out)            // [NB][CH][SH][SW]
{
    __shared__ float red[3 * 64 * 17];  // 13056 B; stride 17: conflict-free

    const int tid  = threadIdx.x;
    const int wv   = tid >> 6;          // wave = frame index
    const int lane = tid & 63;

    // bijective XCD swizzle over 4096 blocks (4096 % 8 == 0)
    const int bid = blockIdx.x;
    const int swz = (bid & 7) * 512 + (bid >> 3);
    // swz bits: [1:0] x-chunk, [9:2] y0, [11:10] nn
    const int x0 = ((swz & 3) << 6) + lane;
    const int y0 = __builtin_amdgcn_readfirstlane((swz >> 2) & (H - 1));
    const int nn = __builtin_amdgcn_readfirstlane(swz >> 10);
    const int a  = __builtin_amdgcn_readfirstlane(wv);

    const bool bL = (x0 > 0);
    const bool bR = (x0 < W - 1);
    const int  xL = bL ? x0 - 1 : 0;
    const int  xR = bR ? x0 + 1 : W - 1;
    const int  iL = y0 * W + xL;
    const int  iC = y0 * W + x0;
    const int  iR = y0 * W + xR;
    const float f2xL = (float)(2 * xL);
    const float f2xC = (float)(2 * x0);
    const float f2xR = (float)(2 * xR);
    const float xf0  = f2xC;
    const float yf0  = (float)(2 * y0);

    // per-subpixel o-matrices (float2 loads, coalesced; redundant per wave)
    const int obase = (nn * SH + 2 * y0) * SW + 2 * x0;
    const float2 v11a = *(const float2*)(o11 + obase);
    const float2 v11b = *(const float2*)(o11 + obase + SW);
    const float2 v12a = *(const float2*)(o12 + obase);
    const float2 v12b = *(const float2*)(o12 + obase + SW);
    const float2 v21a = *(const float2*)(o21 + obase);
    const float2 v21b = *(const float2*)(o21 + obase + SW);
    const float2 v22a = *(const float2*)(o22 + obase);
    const float2 v22b = *(const float2*)(o22 + obase + SW);

    float m11s[2][2], m12s[2][2], m22s[2][2];
    m11s[0][0] = MSCALE * v11a.x;  m11s[0][1] = MSCALE * v11a.y;
    m11s[1][0] = MSCALE * v11b.x;  m11s[1][1] = MSCALE * v11b.y;
    m12s[0][0] = MSCALE * (v12a.x + v21a.x);  m12s[0][1] = MSCALE * (v12a.y + v21a.y);
    m12s[1][0] = MSCALE * (v12b.x + v21b.x);  m12s[1][1] = MSCALE * (v12b.y + v21b.y);
    m22s[0][0] = MSCALE * v22a.x;  m22s[0][1] = MSCALE * v22a.y;
    m22s[1][0] = MSCALE * v22b.x;  m22s[1][1] = MSCALE * v22b.y;

    float sumw[2][2] = {{0.f,0.f},{0.f,0.f}};
    float acc0[2][2] = {{0.f,0.f},{0.f,0.f}};
    float acc1[2][2] = {{0.f,0.f},{0.f,0.f}};
    float acc2[2][2] = {{0.f,0.f},{0.f,0.f}};

    // COLK: one (row,column) contribution to all 4 subpixels.
    // dy/dx Sterbenz-exact; q_ pre-masked for column bounds; no dist clamp.
#define COLK(or_, oc_, q_, a0_, a1_, a2_, f2x_, IS_L, NEED_VY)                \
    {                                                                         \
        const float posr = fmaf(or_, 2.0f, rowf);                             \
        const float dy0v = posr - yf0;                                        \
        const float dy1v = dy0v - 1.0f;                                       \
        const float posc = fmaf(oc_, 2.0f, f2x_);                             \
        const float dx0v = posc - xf0;                                        \
        const float dx1v = dx0v - 1.0f;                                       \
        const bool vx1 = !(IS_L) || (dx1v >= -RADIUS);                        \
        const bool vyb = !(NEED_VY) || (dy1v >= -RADIUS);                     \
        _Pragma("unroll")                                                     \
        for (int sy = 0; sy < 2; ++sy) {                                      \
            const float dyv = sy ? dy1v : dy0v;                               \
            const float dy2 = dyv * dyv;                                      \
            _Pragma("unroll")                                                 \
            for (int sx = 0; sx < 2; ++sx) {                                  \
                const float dxv = sx ? dx1v : dx0v;                           \
                const float u = fmaf(dyv, m12s[sy][sx], dxv * m11s[sy][sx]);  \
                const float d = fmaf(dxv, u, dy2 * m22s[sy][sx]);             \
                float w = __builtin_amdgcn_exp2f(-d) * (q_);                  \
                if (IS_L && sx == 1)    w = vx1 ? w : 0.0f;                   \
                if (NEED_VY && sy == 1) w = vyb ? w : 0.0f;                   \
                sumw[sy][sx] += w;                                            \
                acc0[sy][sx] = fmaf(w, a0_, acc0[sy][sx]);                    \
                acc1[sy][sx] = fmaf(w, a1_, acc1[sy][sx]);                    \
                acc2[sy][sx] = fmaf(w, a2_, acc2[sy][sx]);                    \
            }                                                                 \
        }                                                                     \
    }

    {
        const float* offbR = offsets + (size_t)(a * NB + nn) * 2 * HW;
        const float* offbC = offbR + HW;
        const float* qb    = qs   + (size_t)(a * NB + nn) * HW;
        const float* ab0   = alts + (size_t)(a * NB + nn) * CH * HW;
        const float* ab1   = ab0 + HW;
        const float* ab2   = ab0 + 2 * HW;

        #pragma unroll
        for (int dr = 0; dr < 3; ++dr) {        // dr = di + 1
            if (dr == 0 && y0 == 0) continue;   // scalar uniform skip
            if (dr == 2 && y0 == H - 1) continue;
            const int ro = (dr - 1) * W;        // scalar row offset
            const float* pR = offbR + ro;
            const float* pC = offbC + ro;
            const float* pQ = qb + ro;
            const float* p0 = ab0 + ro;
            const float* p1 = ab1 + ro;
            const float* p2 = ab2 + ro;
            const float rowf = (float)(2 * (y0 + dr - 1));

            // 18 batched scalar gathers (saddr + {iL,iC,iR})
            const float orL = pR[iL], orC = pR[iC], orR = pR[iR];
            const float ocL = pC[iL], ocC = pC[iC], ocR = pC[iR];
            const float qL  = pQ[iL], qC  = pQ[iC], qR  = pQ[iR];
            const float aL0 = p0[iL], aC0 = p0[iC], aR0 = p0[iR];
            const float aL1 = p1[iL], aC1 = p1[iC], aR1 = p1[iR];
            const float aL2 = p2[iL], aC2 = p2[iC], aR2 = p2[iR];

            // column-bounds masks folded into q (once, not per subpixel)
            const float qLm = bL ? qL : 0.0f;
            const float qRm = bR ? qR : 0.0f;

            const bool needvy = (dr == 0);
            COLK(orL, ocL, qLm, aL0, aL1, aL2, f2xL, true,  needvy)
            COLK(orC, ocC, qC,  aC0, aC1, aC2, f2xC, false, needvy)
            COLK(orR, ocR, qRm, aR0, aR1, aR2, f2xR, false, needvy)
        }
    }
#undef COLK

    // 3 writer waves -> LDS; wave 0 reduces, finalizes, stores
    if (wv != 0) {
        float* r = &red[((wv - 1) * 64 + lane) * 17];
        #pragma unroll
        for (int sy = 0; sy < 2; ++sy)
            #pragma unroll
            for (int sx = 0; sx < 2; ++sx) {
                const int s = sy * 2 + sx;
                r[s]      = sumw[sy][sx];
                r[4 + s]  = acc0[sy][sx];
                r[8 + s]  = acc1[sy][sx];
                r[12 + s] = acc2[sy][sx];
            }
    }
    __syncthreads();
    if (wv == 0) {
        #pragma unroll
        for (int w = 0; w < 3; ++w) {
            const float* r = &red[(w * 64 + lane) * 17];
            #pragma unroll
            for (int sy = 0; sy < 2; ++sy)
                #pragma unroll
                for (int sx = 0; sx < 2; ++sx) {
                    const int s = sy * 2 + sx;
                    sumw[sy][sx] += r[s];
                    acc0[sy][sx] += r[4 + s];
                    acc1[sy][sx] += r[8 + s];
                    acc2[sy][sx] += r[12 + s];
                }
        }
        const size_t ob = (size_t)(nn * CH) * SHW + (size_t)(2 * y0) * SW + 2 * x0;
        #pragma unroll
        for (int sy = 0; sy < 2; ++sy) {
            const float i0 = 1.0f / sumw[sy][0];
            const float i1 = 1.0f / sumw[sy][1];
            *(float2*)(out + ob + (size_t)sy * SW) =
                make_float2(acc0[sy][0] * i0, acc0[sy][1] * i1);
            *(float2*)(out + ob + (size_t)sy * SW + SHW) =
                make_float2(acc1[sy][0] * i0, acc1[sy][1] * i1);
            *(float2*)(out + ob + (size_t)sy * SW + 2 * SHW) =
                make_float2(acc2[sy][0] * i0, acc2[sy][1] * i1);
        }
    }
}

extern "C" void kernel_launch(void* const* d_in, const int* in_sizes, int n_in,
                              void* d_out, int out_size, void* d_ws, size_t ws_size,
                              hipStream_t stream) {
    const float* alts    = (const float*)d_in[0];
    const float* offsets = (const float*)d_in[1];
    const float* qs      = (const float*)d_in[2];
    const float* o11     = (const float*)d_in[3];
    const float* o12     = (const float*)d_in[4];
    const float* o21     = (const float*)d_in[5];
    const float* o22     = (const float*)d_in[6];
    float* out = (float*)d_out;

    const int total_threads = NB * H * W * 4;   // 1,048,576 (4 frame-waves/px)
    const int block = 256;
    const int grid  = total_threads / block;    // 4096
    superresolve_kernel<<<grid, block, 0, stream>>>(alts, offsets, qs,
                                                    o11, o12, o21, o22, out);
}